// Round 1
// baseline (91.784 us; speedup 1.0000x reference)
//
#include <hip/hip_runtime.h>

typedef __bf16 bf16x8 __attribute__((ext_vector_type(8)));
typedef float f32x4 __attribute__((ext_vector_type(4)));
typedef unsigned short ushort8 __attribute__((ext_vector_type(8)));

__device__ inline unsigned short f2bf(float f) {
    union { float f; unsigned u; } x; x.f = f;
    unsigned r = x.u + 0x7fffu + ((x.u >> 16) & 1u);
    return (unsigned short)(r >> 16);
}
__device__ inline float bf2f(unsigned short u) {
    union { unsigned u; float f; } x; x.u = ((unsigned)u) << 16;
    return x.f;
}

// ---------------------------------------------------------------------------
// K0: src/dst = relu(LN(node @ W^T + b)); also A1 = src@W1a^T + b1, B1 = dst@W1b^T
// One wave per (row, kind). kind 0 = src, 1 = dst.
// ---------------------------------------------------------------------------
__global__ __launch_bounds__(256) void proj_kernel(
    const float* __restrict__ node,
    const float* __restrict__ w_src, const float* __restrict__ b_src,
    const float* __restrict__ g_src, const float* __restrict__ be_src,
    const float* __restrict__ w_dst, const float* __restrict__ b_dst,
    const float* __restrict__ g_dst, const float* __restrict__ be_dst,
    const float* __restrict__ w1, const float* __restrict__ b1,
    unsigned short* __restrict__ src_bf, unsigned short* __restrict__ dst_bf,
    float* __restrict__ A1, float* __restrict__ B1)
{
    __shared__ float rowbuf[4][64];
    const int wloc = threadIdx.x >> 6;
    const int lane = threadIdx.x & 63;
    const int gw = blockIdx.x * 4 + wloc;     // 0..2047
    const int row = gw & 1023;
    const int kind = gw >> 10;

    const float* W  = kind ? w_dst  : w_src;
    const float* Bv = kind ? b_dst  : b_src;
    const float* G  = kind ? g_dst  : g_src;
    const float* BE = kind ? be_dst : be_src;

    const float* nrow = node + row * 128;
    const float* wrow = W + lane * 128;
    float acc = Bv[lane];
    #pragma unroll 8
    for (int k = 0; k < 128; k += 4) {
        float4 nv = *(const float4*)(nrow + k);
        float4 wv4 = *(const float4*)(wrow + k);
        acc += nv.x * wv4.x + nv.y * wv4.y + nv.z * wv4.z + nv.w * wv4.w;
    }
    // LayerNorm over 64 lanes
    float s = acc;
    #pragma unroll
    for (int off = 32; off >= 1; off >>= 1) s += __shfl_xor(s, off);
    float mean = s * (1.0f / 64.0f);
    float d = acc - mean;
    float ss = d * d;
    #pragma unroll
    for (int off = 32; off >= 1; off >>= 1) ss += __shfl_xor(ss, off);
    float rstd = rsqrtf(ss * (1.0f / 64.0f) + 1e-5f);
    float y = fmaxf(d * rstd * G[lane] + BE[lane], 0.0f);

    unsigned short* obf = kind ? dst_bf : src_bf;
    obf[row * 64 + lane] = f2bf(y);

    rowbuf[wloc][lane] = y;
    __builtin_amdgcn_s_waitcnt(0);  // within-wave LDS RAW; compiler also tracks
    // A1[row][m] = sum_k y[k]*w1[m][koff+k] (+ b1[m] for src side)
    float* outA = kind ? B1 : A1;
    const int koff = kind * 64;
    float a0 = kind ? 0.0f : b1[lane];
    float a1 = kind ? 0.0f : b1[lane + 64];
    const float* w1r0 = w1 + (size_t)lane * 192 + koff;
    const float* w1r1 = w1 + (size_t)(lane + 64) * 192 + koff;
    #pragma unroll 8
    for (int k = 0; k < 64; k++) {
        float yv = rowbuf[wloc][k];
        a0 += yv * w1r0[k];
        a1 += yv * w1r1[k];
    }
    outA[row * 128 + lane] = a0;
    outA[row * 128 + lane + 64] = a1;
}

// ---------------------------------------------------------------------------
// K0c: pack w1c (= w1[:,128:192]) and w2 into MFMA B-fragment order (bf16).
// B-frag layout for 16x16x32: lane l holds B[k][n] with n = l&15, k = (l>>4)*8+e.
// w1c: frag f = kt*8+nt (kt<2, nt<8). w2: frag f = kt*4+nt (kt<4, nt<4).
// ---------------------------------------------------------------------------
__global__ __launch_bounds__(256) void pack_kernel(
    const float* __restrict__ w1, const float* __restrict__ w2,
    unsigned short* __restrict__ w1c_frag, unsigned short* __restrict__ w2_frag)
{
    int t = blockIdx.x * 256 + threadIdx.x;   // 0..2047
    int which = t >> 10;
    int idx = t & 1023;                       // f*64 + l
    int f = idx >> 6, l = idx & 63;
    int lq = l >> 4, lr = l & 15;
    if (which == 0) {
        int kt = f >> 3, nt = f & 7;
        int n = nt * 16 + lr;
        #pragma unroll
        for (int e = 0; e < 8; e++) {
            int k = kt * 32 + lq * 8 + e;
            w1c_frag[idx * 8 + e] = f2bf(w1[n * 192 + 128 + k]);
        }
    } else {
        int kt = f >> 2, nt = f & 3;
        int n = nt * 16 + lr;
        #pragma unroll
        for (int e = 0; e < 8; e++) {
            int k = kt * 32 + lq * 8 + e;
            w2_frag[idx * 8 + e] = f2bf(w2[n * 128 + k]);
        }
    }
}

// ---------------------------------------------------------------------------
// K1: pairwise MLP. 32x32 pair tile per WG, 4 waves, 16-pair chunks per wave.
// chunk = (fixed i, 16 consecutive j). GEMM1: cross term only (K=64, N=128).
// h1 = relu(acc + A1[i] + B1[j]); GEMM2: K=128, N=64; GEMM3 on VALU.
// ---------------------------------------------------------------------------
__global__ __launch_bounds__(256, 2) void pair_kernel(
    const unsigned short* __restrict__ src_bf, const unsigned short* __restrict__ dst_bf,
    const float* __restrict__ A1, const float* __restrict__ B1,
    const unsigned short* __restrict__ w1c_frag, const unsigned short* __restrict__ w2_frag,
    const float* __restrict__ b2, const float* __restrict__ w3,
    const float* __restrict__ b3, float* __restrict__ out)
{
    __shared__ __align__(16) unsigned short s_src[32][72];
    __shared__ __align__(16) unsigned short s_dst[32][72];
    __shared__ __align__(16) float s_A1[32][132];
    __shared__ __align__(16) float s_B1[32][132];
    __shared__ __align__(16) unsigned short s_h1[4][16][136];

    const int tid = threadIdx.x;
    const int wv = tid >> 6;
    const int lane = tid & 63;
    const int lq = lane >> 4, lr = lane & 15;
    const int i0 = blockIdx.y * 32, j0 = blockIdx.x * 32;

    // ---- stage tiles ----
    {
        int r = tid >> 3;
        int c = (tid & 7) * 8;
        *(uint4*)(&s_src[r][c]) = *(const uint4*)(src_bf + (i0 + r) * 64 + c);
        *(uint4*)(&s_dst[r][c]) = *(const uint4*)(dst_bf + (j0 + r) * 64 + c);
        int c2 = (tid & 7) * 16;
        #pragma unroll
        for (int u = 0; u < 4; u++) {
            *(float4*)(&s_A1[r][c2 + u * 4]) = *(const float4*)(A1 + (i0 + r) * 128 + c2 + u * 4);
            *(float4*)(&s_B1[r][c2 + u * 4]) = *(const float4*)(B1 + (j0 + r) * 128 + c2 + u * 4);
        }
    }

    // ---- preload weight fragments into registers ----
    bf16x8 w1f[2][8], w2f[4][4];
    {
        const uint4* wp = (const uint4*)w1c_frag;
        #pragma unroll
        for (int kt = 0; kt < 2; kt++)
            #pragma unroll
            for (int nt = 0; nt < 8; nt++)
                w1f[kt][nt] = __builtin_bit_cast(bf16x8, wp[(kt * 8 + nt) * 64 + lane]);
        const uint4* wp2 = (const uint4*)w2_frag;
        #pragma unroll
        for (int kt = 0; kt < 4; kt++)
            #pragma unroll
            for (int nt = 0; nt < 4; nt++)
                w2f[kt][nt] = __builtin_bit_cast(bf16x8, wp2[(kt * 4 + nt) * 64 + lane]);
    }
    float b2v[4], w3v[4];
    #pragma unroll
    for (int nt = 0; nt < 4; nt++) {
        b2v[nt] = b2[nt * 16 + lr];
        w3v[nt] = w3[nt * 16 + lr];
    }
    const float b3v = b3[0];

    __syncthreads();

    // ---- 16 chunks of 16 pairs per wave ----
    for (int cc = 0; cc < 16; cc++) {
        const int c = wv * 16 + cc;
        const int i_loc = c >> 1;
        const int jb = (c & 1) * 16;

        // build cross-feature A fragments: cross[p][k] = src[i][k]*dst[jb+p][k]
        bf16x8 ca[2];
        #pragma unroll
        for (int kt = 0; kt < 2; kt++) {
            ushort8 sv = *(const ushort8*)(&s_src[i_loc][kt * 32 + lq * 8]);
            ushort8 dv = *(const ushort8*)(&s_dst[jb + lr][kt * 32 + lq * 8]);
            ushort8 cu;
            #pragma unroll
            for (int e = 0; e < 8; e++)
                cu[e] = f2bf(bf2f(sv[e]) * bf2f(dv[e]));
            ca[kt] = __builtin_bit_cast(bf16x8, cu);
        }

        // GEMM1 (cross): M=16 pairs, K=64, N=128
        f32x4 acc1[8];
        #pragma unroll
        for (int nt = 0; nt < 8; nt++) acc1[nt] = (f32x4){0.f, 0.f, 0.f, 0.f};
        #pragma unroll
        for (int kt = 0; kt < 2; kt++)
            #pragma unroll
            for (int nt = 0; nt < 8; nt++)
                acc1[nt] = __builtin_amdgcn_mfma_f32_16x16x32_bf16(ca[kt], w1f[kt][nt], acc1[nt], 0, 0, 0);

        // epilogue1: + A1[i] + B1[j], relu, bf16 -> s_h1 (per-wave region)
        #pragma unroll
        for (int nt = 0; nt < 8; nt++) {
            float a1v = s_A1[i_loc][nt * 16 + lr];
            #pragma unroll
            for (int r = 0; r < 4; r++) {
                int p = lq * 4 + r;
                float v = acc1[nt][r] + a1v + s_B1[jb + p][nt * 16 + lr];
                v = fmaxf(v, 0.0f);
                s_h1[wv][p][nt * 16 + lr] = f2bf(v);
            }
        }

        // GEMM2: M=16 pairs, K=128, N=64
        bf16x8 a2[4];
        #pragma unroll
        for (int kt = 0; kt < 4; kt++)
            a2[kt] = __builtin_bit_cast(bf16x8, *(const ushort8*)(&s_h1[wv][lr][kt * 32 + lq * 8]));
        f32x4 acc2[4];
        #pragma unroll
        for (int nt = 0; nt < 4; nt++) acc2[nt] = (f32x4){b2v[nt], b2v[nt], b2v[nt], b2v[nt]};
        #pragma unroll
        for (int kt = 0; kt < 4; kt++)
            #pragma unroll
            for (int nt = 0; nt < 4; nt++)
                acc2[nt] = __builtin_amdgcn_mfma_f32_16x16x32_bf16(a2[kt], w2f[kt][nt], acc2[nt], 0, 0, 0);

        // GEMM3: relu(h2) . w3, reduce over 64 cols (16 lanes x 4 frags)
        float sr[4];
        #pragma unroll
        for (int r = 0; r < 4; r++) {
            float acc = 0.f;
            #pragma unroll
            for (int nt = 0; nt < 4; nt++)
                acc += fmaxf(acc2[nt][r], 0.0f) * w3v[nt];
            sr[r] = acc;
        }
        #pragma unroll
        for (int off = 1; off < 16; off <<= 1)
            #pragma unroll
            for (int r = 0; r < 4; r++)
                sr[r] += __shfl_xor(sr[r], off);

        if (lr == 0) {
            int i = i0 + i_loc;
            int jbase = j0 + jb + lq * 4;
            #pragma unroll
            for (int r = 0; r < 4; r++)
                out[(size_t)i * 1024 + jbase + r] = sr[r] + b3v;
        }
    }
}

// ---------------------------------------------------------------------------
extern "C" void kernel_launch(void* const* d_in, const int* in_sizes, int n_in,
                              void* d_out, int out_size, void* d_ws, size_t ws_size,
                              hipStream_t stream) {
    (void)in_sizes; (void)n_in; (void)out_size; (void)ws_size;
    const float* node   = (const float*)d_in[0];
    const float* w_src  = (const float*)d_in[1];
    const float* b_src  = (const float*)d_in[2];
    const float* g_src  = (const float*)d_in[3];
    const float* be_src = (const float*)d_in[4];
    const float* w_dst  = (const float*)d_in[5];
    const float* b_dst  = (const float*)d_in[6];
    const float* g_dst  = (const float*)d_in[7];
    const float* be_dst = (const float*)d_in[8];
    const float* w1     = (const float*)d_in[9];
    const float* b1     = (const float*)d_in[10];
    const float* w2     = (const float*)d_in[11];
    const float* b2     = (const float*)d_in[12];
    const float* w3     = (const float*)d_in[13];
    const float* b3     = (const float*)d_in[14];

    char* ws = (char*)d_ws;
    unsigned short* src_bf   = (unsigned short*)(ws);
    unsigned short* dst_bf   = (unsigned short*)(ws + 131072);
    float*          A1       = (float*)(ws + 262144);
    float*          B1       = (float*)(ws + 786432);
    unsigned short* w1c_frag = (unsigned short*)(ws + 1310720);
    unsigned short* w2_frag  = (unsigned short*)(ws + 1327104);

    hipLaunchKernelGGL(proj_kernel, dim3(512), dim3(256), 0, stream,
                       node, w_src, b_src, g_src, be_src, w_dst, b_dst, g_dst, be_dst,
                       w1, b1, src_bf, dst_bf, A1, B1);
    hipLaunchKernelGGL(pack_kernel, dim3(8), dim3(256), 0, stream,
                       w1, w2, w1c_frag, w2_frag);
    hipLaunchKernelGGL(pair_kernel, dim3(32, 32), dim3(256), 0, stream,
                       src_bf, dst_bf, A1, B1, w1c_frag, w2_frag, b2, w3, b3,
                       (float*)d_out);
}